// Round 3
// baseline (2803.358 us; speedup 1.0000x reference)
//
#include <hip/hip_runtime.h>

// LSTM (H=32), B=2048, T=1024, prefix-masked + mean pool + sigmoid classifier.
// 3 kernels: (1) lengths from mask, (2) one-block counting sort of batch
// indices by length, (3) main LSTM.
//
// v4: dual-sequence waves (scheduler-independent load balance).
//  Round-2 evidence: occupancy 13% + 615us match a dispatch model where
//  small-stride blocks share a SIMD -> static cross-block pairing of
//  short+long sequences is unreliable. Instead each wave now runs TWO
//  sequences: lanes 0-31 = seq A, lanes 32-63 = seq B. Each lane owns all
//  four gate rows (i,f,g,o) of one output index:
//   - gates are fully lane-local (no cross-half exchange at all),
//   - x/h broadcasts use ds_swizzle_b32 (broadcast lane i within each
//     32-lane group, offset i<<5) on the LDS pipe -> zero v_readlane
//     (removes VALU->SGPR hazard stalls), VALU does only pk_fma + gates.
//  Pairing ranks (2q, 2q+1) = nearly equal lengths -> intra-wave idle ~0;
//  makespan = L_max * per-step cost independent of block->SIMD mapping.
//  Weights: 256 floats/lane > 256 arch-VGPR limit, so h-part weights are
//  pinned "+v" (latency-critical path in arch VGPRs) and x-part weights
//  pinned "+a" (AGPRs; any copies overlap the gate chain). 1 wave/SIMD via
//  amdgpu_waves_per_eu(1,1).

typedef float v2f __attribute__((ext_vector_type(2)));

__device__ __forceinline__ float fast_sigmoid(float x) {
    return __builtin_amdgcn_rcpf(1.0f + __expf(-x));
}
__device__ __forceinline__ float fast_tanh(float x) {
    return fmaf(2.0f, fast_sigmoid(2.0f * x), -1.0f);
}
__device__ __forceinline__ v2f splat2(float x) { v2f r; r.x = x; r.y = x; return r; }
__device__ __forceinline__ v2f fma2(v2f a, v2f b, v2f c) {
#if __has_builtin(__builtin_elementwise_fma)
    return __builtin_elementwise_fma(a, b, c);
#else
    v2f r; r.x = fmaf(a.x, b.x, c.x); r.y = fmaf(a.y, b.y, c.y); return r;
#endif
}

// broadcast lane i within each 32-lane group (BitMode: and=0, or=i, xor=0)
#define BC(v, i) __int_as_float(__builtin_amdgcn_ds_swizzle(__float_as_int(v), ((i) << 5)))

// ---- macro machinery: 128 v2f weight registers per lane ----
#define R16A(M) M(0) M(1) M(2) M(3) M(4) M(5) M(6) M(7) \
                M(8) M(9) M(10) M(11) M(12) M(13) M(14) M(15)
#define R16B(M) M(16) M(17) M(18) M(19) M(20) M(21) M(22) M(23) \
                M(24) M(25) M(26) M(27) M(28) M(29) M(30) M(31)
#define R32(M) R16A(M) R16B(M)

#define DECLW(i) v2f wiIF_##i, wiGO_##i, whIF_##i, whGO_##i;
#define LOADW(i) \
    wiIF_##i.x = w_ih[rI + (i)]; wiIF_##i.y = w_ih[rF + (i)]; \
    wiGO_##i.x = w_ih[rG + (i)]; wiGO_##i.y = w_ih[rO + (i)]; \
    whIF_##i.x = w_hh[rI + (i)]; whIF_##i.y = w_hh[rF + (i)]; \
    whGO_##i.x = w_hh[rG + (i)]; whGO_##i.y = w_hh[rO + (i)];
// pins: h-part weights must be arch VGPRs; x-part weights live in AGPRs
#define PINW(i) asm volatile("" : "+v"(whIF_##i), "+v"(whGO_##i)); \
                asm volatile("" : "+a"(wiIF_##i), "+a"(wiGO_##i));

// x-part FMAs: cols 0-15 -> acc0, cols 16-31 -> acc1
#define XP0(i) { const v2f xm = splat2(BC(xq, i)); \
                 axIF0 = fma2(xm, wiIF_##i, axIF0); axGO0 = fma2(xm, wiGO_##i, axGO0); }
#define XP1(i) { const v2f xm = splat2(BC(xq, i)); \
                 axIF1 = fma2(xm, wiIF_##i, axIF1); axGO1 = fma2(xm, wiGO_##i, axGO1); }
// h-part FMAs
#define HP0(i) { const v2f hm = splat2(BC(h, i)); \
                 ahIF0 = fma2(hm, whIF_##i, ahIF0); ahGO0 = fma2(hm, whGO_##i, ahGO0); }
#define HP1(i) { const v2f hm = splat2(BC(h, i)); \
                 ahIF1 = fma2(hm, whIF_##i, ahIF1); ahGO1 = fma2(hm, whGO_##i, ahGO1); }

// ---- kernel 1: sequence lengths from prefix mask ----
__global__ __launch_bounds__(64)
void len_kernel(const float* __restrict__ mask, int* __restrict__ lens, int B, int T)
{
    const int b = blockIdx.x;
    if (b >= B) return;
    const int lane = threadIdx.x;
    const float4* m4 = (const float4*)(mask + (size_t)b * T);
    float s = 0.0f;
    for (int i = lane; i < (T >> 2); i += 64) {
        const float4 v = m4[i];
        s += (v.x + v.y) + (v.z + v.w);
    }
#pragma unroll
    for (int off = 32; off > 0; off >>= 1) s += __shfl_down(s, off, 64);
    if (lane == 0) lens[b] = (int)(s + 0.5f);
}

// ---- kernel 2: one-block counting sort (ascending length) ----
__global__ __launch_bounds__(1024)
void sort_kernel(const int* __restrict__ lens, int* __restrict__ sortedIdx, int B, int T)
{
    __shared__ int hist[1024];
    __shared__ int scan[1024];
    __shared__ int cur[1024];
    const int tid = threadIdx.x;
    if (tid < T) hist[tid] = 0;
    __syncthreads();
    for (int b = tid; b < B; b += blockDim.x)
        atomicAdd(&hist[lens[b] - 1], 1);
    __syncthreads();
    if (tid < T) scan[tid] = hist[tid];
    __syncthreads();
    for (int off = 1; off < T; off <<= 1) {          // Hillis-Steele inclusive
        int v = 0;
        if (tid >= off && tid < T) v = scan[tid - off];
        __syncthreads();
        if (tid < T) scan[tid] += v;
        __syncthreads();
    }
    if (tid < T) cur[tid] = scan[tid] - hist[tid];   // exclusive prefix
    __syncthreads();
    for (int b = tid; b < B; b += blockDim.x) {
        const int pos = atomicAdd(&cur[lens[b] - 1], 1);
        sortedIdx[pos] = b;
    }
}

// ---- kernel 3: main LSTM, TWO sequences per wave (one per 32-lane half) ----
__global__ __launch_bounds__(64) __attribute__((amdgpu_waves_per_eu(1, 1)))
void lstm_main(const float* __restrict__ x,        // [B,T,32]
               const int* __restrict__ lens,       // [B]
               const int* __restrict__ sortedIdx,  // [B]
               const float* __restrict__ w_ih,     // [128,32]
               const float* __restrict__ w_hh,     // [128,32]
               const float* __restrict__ b_ih,     // [128]
               const float* __restrict__ b_hh,     // [128]
               const float* __restrict__ w_cls,    // [1,32]
               const float* __restrict__ b_cls,    // [1]
               float* __restrict__ out,            // pooled [B,32] ++ probs [B]
               int B, int T)
{
    const int q = blockIdx.x;                      // 0 .. B/2-1
    const int lane = threadIdx.x;
    const int lm = lane & 31;                      // output index within seq
    const bool lo = (lane < 32);                   // half: seq A vs seq B
    // per-lane gate rows (PyTorch order i,f,g,o)
    const int rI = lm * 32, rF = (lm + 32) * 32, rG = (lm + 64) * 32, rO = (lm + 96) * 32;
    const int Tm1 = T - 1;

    R32(DECLW)
    R32(LOADW)

    v2f biasIF, biasGO;
    biasIF.x = b_ih[lm]      + b_hh[lm];
    biasIF.y = b_ih[lm + 32] + b_hh[lm + 32];
    biasGO.x = b_ih[lm + 64] + b_hh[lm + 64];
    biasGO.y = b_ih[lm + 96] + b_hh[lm + 96];

    // adjacent sorted ranks: nearly equal lengths -> minimal intra-wave idle
    const int bA = sortedIdx[2 * q];
    const int bB = sortedIdx[2 * q + 1];
    const int LA = lens[bA];
    const int LB = lens[bB];
    const int bsel = lo ? bA : bB;
    const int Lsel = lo ? LA : LB;
    const int Lw = LA > LB ? LA : LB;
    const float* xb = x + (size_t)bsel * T * 32;

    float h = 0.0f, c = 0.0f, hsum = 0.0f;

    // prime: x-part of step 0
    float xq = xb[lm];                                     // x_0 (own seq)
    v2f axIF0 = biasIF, axIF1 = splat2(0.0f);
    v2f axGO0 = biasGO, axGO1 = splat2(0.0f);
    R16A(XP0) R16B(XP1)
    v2f axIF0c = axIF0, axIF1c = axIF1, axGO0c = axGO0, axGO1c = axGO1;
    xq = xb[min(1, Tm1) * 32 + lm];                        // x_1

    for (int t = 0; t < Lw; ++t) {
        R32(PINW)                                          // keep weights resident
        const float xn = xb[min(t + 2, Tm1) * 32 + lm];    // prefetch x_{t+2}
        // h-part of step t (h holds h_t[lm] of own seq on every lane)
        v2f ahIF0 = splat2(0.0f), ahIF1 = splat2(0.0f);
        v2f ahGO0 = splat2(0.0f), ahGO1 = splat2(0.0f);
        R16A(HP0) R16B(HP1)
        const v2f preIF = (axIF0c + ahIF0) + (axIF1c + ahIF1);
        const v2f preGO = (axGO0c + ahGO0) + (axGO1c + ahGO1);
        const float ig = fast_sigmoid(preIF.x);
        const float fg = fast_sigmoid(preIF.y);
        const float gg = fast_tanh(preGO.x);
        const float og = fast_sigmoid(preGO.y);
        c = fmaf(fg, c, ig * gg);
        h = og * fast_tanh(c);
        hsum += (t < Lsel) ? h : 0.0f;                     // mask finished half
        // x-part of step t+1 (independent of h-chain -> fills gate latency)
        axIF0 = biasIF; axIF1 = splat2(0.0f);
        axGO0 = biasGO; axGO1 = splat2(0.0f);
        R16A(XP0) R16B(XP1)
        axIF0c = axIF0; axIF1c = axIF1; axGO0c = axGO0; axGO1c = axGO1;
        xq = xn;
    }

    const float pooled = hsum / (float)Lsel;               // Lsel >= 1 always
    out[(size_t)bsel * 32 + lm] = pooled;                  // both halves write

    float contrib = pooled * w_cls[lm];
#pragma unroll
    for (int off = 16; off > 0; off >>= 1)                 // reduce within half
        contrib += __shfl_down(contrib, off, 32);
    if (lm == 0)
        out[(size_t)B * 32 + bsel] = fast_sigmoid(contrib + b_cls[0]);
}

extern "C" void kernel_launch(void* const* d_in, const int* in_sizes, int n_in,
                              void* d_out, int out_size, void* d_ws, size_t ws_size,
                              hipStream_t stream)
{
    const float* x     = (const float*)d_in[0];
    const float* mask  = (const float*)d_in[1];
    const float* w_ih  = (const float*)d_in[2];
    const float* w_hh  = (const float*)d_in[3];
    const float* b_ih  = (const float*)d_in[4];
    const float* b_hh  = (const float*)d_in[5];
    const float* w_cls = (const float*)d_in[6];
    const float* b_cls = (const float*)d_in[7];
    float* out = (float*)d_out;

    const int B = out_size / 33;        // pooled B*32 + probs B
    const int T = in_sizes[1] / B;      // mask is [B,T]

    int* lens = (int*)d_ws;
    int* sidx = lens + B;

    len_kernel<<<B, 64, 0, stream>>>(mask, lens, B, T);
    sort_kernel<<<1, 1024, 0, stream>>>(lens, sidx, B, T);
    lstm_main<<<B / 2, 64, 0, stream>>>(x, lens, sidx, w_ih, w_hh, b_ih, b_hh,
                                        w_cls, b_cls, out, B, T);
}

// Round 4
// 2595.524 us; speedup vs baseline: 1.0801x; 1.0801x over previous
//
#include <hip/hip_runtime.h>

// LSTM (H=32), B=2048, T=1024, prefix-masked + mean pool + sigmoid classifier.
// 3 kernels: (1) lengths from mask, (2) one-block counting sort of batch
// indices by length, (3) main LSTM.
//
// v5: dual-sequence waves, schedule un-poisoned.
//  v4 postmortem: VALUBusy 10.5%, ~6000 cyc/step -- the 32 asm-volatile
//  weight pins INSIDE the loop were scheduling barriers that serialized
//  every ds_swizzle into issue->wait->use (64 x ~90cyc exposed LDS latency
//  per step). Fixes:
//   - pins hoisted out of the loop (once after load): w_hh "+v" (arch
//     VGPRs, h-part is the critical path), w_ih "+a" (AGPRs, unified file;
//     x-phase tolerates any access cost).
//   - swizzle broadcasts explicitly BATCHED: 32 ds_swizzle(h) into named
//     temps, then 32 pk_fma pairs; x-broadcasts issued right after so
//     their latency hides under the gate/c/h VALU chain.
//   - zero asm / barriers in the loop: compiler free to overlap the
//     independent x-phase with h-phase waits (ILP replaces TLP at
//     1 wave/SIMD).
//  Structure kept from v4: lanes 0-31 = seq A, lanes 32-63 = seq B
//  (ranks 2q, 2q+1 -> near-equal lengths, scheduler-independent balance);
//  each lane owns all four gate rows (i,f,g,o) of one output index ->
//  gates fully lane-local, no cross-half exchange.

typedef float v2f __attribute__((ext_vector_type(2)));

__device__ __forceinline__ float fast_sigmoid(float x) {
    return __builtin_amdgcn_rcpf(1.0f + __expf(-x));
}
__device__ __forceinline__ float fast_tanh(float x) {
    return fmaf(2.0f, fast_sigmoid(2.0f * x), -1.0f);
}
__device__ __forceinline__ v2f splat2(float x) { v2f r; r.x = x; r.y = x; return r; }
__device__ __forceinline__ v2f fma2(v2f a, v2f b, v2f c) {
#if __has_builtin(__builtin_elementwise_fma)
    return __builtin_elementwise_fma(a, b, c);
#else
    v2f r; r.x = fmaf(a.x, b.x, c.x); r.y = fmaf(a.y, b.y, c.y); return r;
#endif
}

// broadcast lane i within each 32-lane group (BitMode: and=0, or=i, xor=0)
#define BC(v, i) __int_as_float(__builtin_amdgcn_ds_swizzle(__float_as_int(v), ((i) << 5)))

// ---- macro machinery ----
#define R16A(M) M(0) M(1) M(2) M(3) M(4) M(5) M(6) M(7) \
                M(8) M(9) M(10) M(11) M(12) M(13) M(14) M(15)
#define R16B(M) M(16) M(17) M(18) M(19) M(20) M(21) M(22) M(23) \
                M(24) M(25) M(26) M(27) M(28) M(29) M(30) M(31)
#define R32(M) R16A(M) R16B(M)

#define DECLW(i) v2f wiIF_##i, wiGO_##i, whIF_##i, whGO_##i;
#define LOADW(i) \
    wiIF_##i.x = w_ih[rI + (i)]; wiIF_##i.y = w_ih[rF + (i)]; \
    wiGO_##i.x = w_ih[rG + (i)]; wiGO_##i.y = w_ih[rO + (i)]; \
    whIF_##i.x = w_hh[rI + (i)]; whIF_##i.y = w_hh[rF + (i)]; \
    whGO_##i.x = w_hh[rG + (i)]; whGO_##i.y = w_hh[rO + (i)];
// one-time pins (OUTSIDE the loop): h-weights arch VGPR, x-weights AGPR
#define PINW(i) asm volatile("" : "+v"(whIF_##i), "+v"(whGO_##i)); \
                asm volatile("" : "+a"(wiIF_##i), "+a"(wiGO_##i));

#define DECLT(i) float t_##i;
// batched broadcasts
#define SWZH(i) t_##i = BC(h, i);
#define SWZX(i) t_##i = BC(xq, i);
// batched FMAs (two accumulator sets to halve dependent-chain depth)
#define FMH0(i) { const v2f m = splat2(t_##i); \
                  ahIF0 = fma2(m, whIF_##i, ahIF0); ahGO0 = fma2(m, whGO_##i, ahGO0); }
#define FMH1(i) { const v2f m = splat2(t_##i); \
                  ahIF1 = fma2(m, whIF_##i, ahIF1); ahGO1 = fma2(m, whGO_##i, ahGO1); }
#define FMX0(i) { const v2f m = splat2(t_##i); \
                  axIF0 = fma2(m, wiIF_##i, axIF0); axGO0 = fma2(m, wiGO_##i, axGO0); }
#define FMX1(i) { const v2f m = splat2(t_##i); \
                  axIF1 = fma2(m, wiIF_##i, axIF1); axGO1 = fma2(m, wiGO_##i, axGO1); }

// ---- kernel 1: sequence lengths from prefix mask ----
__global__ __launch_bounds__(64)
void len_kernel(const float* __restrict__ mask, int* __restrict__ lens, int B, int T)
{
    const int b = blockIdx.x;
    if (b >= B) return;
    const int lane = threadIdx.x;
    const float4* m4 = (const float4*)(mask + (size_t)b * T);
    float s = 0.0f;
    for (int i = lane; i < (T >> 2); i += 64) {
        const float4 v = m4[i];
        s += (v.x + v.y) + (v.z + v.w);
    }
#pragma unroll
    for (int off = 32; off > 0; off >>= 1) s += __shfl_down(s, off, 64);
    if (lane == 0) lens[b] = (int)(s + 0.5f);
}

// ---- kernel 2: one-block counting sort (ascending length) ----
__global__ __launch_bounds__(1024)
void sort_kernel(const int* __restrict__ lens, int* __restrict__ sortedIdx, int B, int T)
{
    __shared__ int hist[1024];
    __shared__ int scan[1024];
    __shared__ int cur[1024];
    const int tid = threadIdx.x;
    if (tid < T) hist[tid] = 0;
    __syncthreads();
    for (int b = tid; b < B; b += blockDim.x)
        atomicAdd(&hist[lens[b] - 1], 1);
    __syncthreads();
    if (tid < T) scan[tid] = hist[tid];
    __syncthreads();
    for (int off = 1; off < T; off <<= 1) {          // Hillis-Steele inclusive
        int v = 0;
        if (tid >= off && tid < T) v = scan[tid - off];
        __syncthreads();
        if (tid < T) scan[tid] += v;
        __syncthreads();
    }
    if (tid < T) cur[tid] = scan[tid] - hist[tid];   // exclusive prefix
    __syncthreads();
    for (int b = tid; b < B; b += blockDim.x) {
        const int pos = atomicAdd(&cur[lens[b] - 1], 1);
        sortedIdx[pos] = b;
    }
}

// ---- kernel 3: main LSTM, TWO sequences per wave (one per 32-lane half) ----
__global__ __launch_bounds__(64) __attribute__((amdgpu_waves_per_eu(1, 1)))
void lstm_main(const float* __restrict__ x,        // [B,T,32]
               const int* __restrict__ lens,       // [B]
               const int* __restrict__ sortedIdx,  // [B]
               const float* __restrict__ w_ih,     // [128,32]
               const float* __restrict__ w_hh,     // [128,32]
               const float* __restrict__ b_ih,     // [128]
               const float* __restrict__ b_hh,     // [128]
               const float* __restrict__ w_cls,    // [1,32]
               const float* __restrict__ b_cls,    // [1]
               float* __restrict__ out,            // pooled [B,32] ++ probs [B]
               int B, int T)
{
    const int q = blockIdx.x;                      // 0 .. B/2-1
    const int lane = threadIdx.x;
    const int lm = lane & 31;                      // output index within seq
    const bool lo = (lane < 32);                   // half: seq A vs seq B
    // per-lane gate rows (PyTorch order i,f,g,o)
    const int rI = lm * 32, rF = (lm + 32) * 32, rG = (lm + 64) * 32, rO = (lm + 96) * 32;
    const int Tm1 = T - 1;

    R32(DECLW)
    R32(LOADW)
    R32(PINW)                                      // ONCE, outside the loop
    R32(DECLT)

    v2f biasIF, biasGO;
    biasIF.x = b_ih[lm]      + b_hh[lm];
    biasIF.y = b_ih[lm + 32] + b_hh[lm + 32];
    biasGO.x = b_ih[lm + 64] + b_hh[lm + 64];
    biasGO.y = b_ih[lm + 96] + b_hh[lm + 96];

    // adjacent sorted ranks: nearly equal lengths -> minimal intra-wave idle
    const int bA = sortedIdx[2 * q];
    const int bB = sortedIdx[2 * q + 1];
    const int LA = lens[bA];
    const int LB = lens[bB];
    const int bsel = lo ? bA : bB;
    const int Lsel = lo ? LA : LB;
    const int Lw = LA > LB ? LA : LB;
    const float* xb = x + (size_t)bsel * T * 32;

    float h = 0.0f, c = 0.0f, hsum = 0.0f;

    // prime: x-part of step 0
    float xq = xb[lm];                                     // x_0 (own seq)
    v2f axIF0 = biasIF, axIF1 = splat2(0.0f);
    v2f axGO0 = biasGO, axGO1 = splat2(0.0f);
    R32(SWZX)
    R16A(FMX0) R16B(FMX1)
    v2f axIF0c = axIF0, axIF1c = axIF1, axGO0c = axGO0, axGO1c = axGO1;
    xq = xb[min(1, Tm1) * 32 + lm];                        // x_1

    for (int t = 0; t < Lw; ++t) {
        const float xn = xb[min(t + 2, Tm1) * 32 + lm];    // prefetch x_{t+2}
        // ---- h-part of step t: 32 batched swizzles, then 32 batched FMAs
        v2f ahIF0 = splat2(0.0f), ahIF1 = splat2(0.0f);
        v2f ahGO0 = splat2(0.0f), ahGO1 = splat2(0.0f);
        R32(SWZH)
        R16A(FMH0) R16B(FMH1)
        // ---- x-part broadcasts for step t+1: issue now, consume after the
        //      gate chain (their LDS latency hides under ~80cyc of VALU)
        R32(SWZX)
        const v2f preIF = (axIF0c + ahIF0) + (axIF1c + ahIF1);
        const v2f preGO = (axGO0c + ahGO0) + (axGO1c + ahGO1);
        const float ig = fast_sigmoid(preIF.x);
        const float fg = fast_sigmoid(preIF.y);
        const float gg = fast_tanh(preGO.x);
        const float og = fast_sigmoid(preGO.y);
        c = fmaf(fg, c, ig * gg);
        h = og * fast_tanh(c);
        hsum += (t < Lsel) ? h : 0.0f;                     // mask finished half
        // ---- x-part FMAs for step t+1
        axIF0 = biasIF; axIF1 = splat2(0.0f);
        axGO0 = biasGO; axGO1 = splat2(0.0f);
        R16A(FMX0) R16B(FMX1)
        axIF0c = axIF0; axIF1c = axIF1; axGO0c = axGO0; axGO1c = axGO1;
        xq = xn;
    }

    const float pooled = hsum / (float)Lsel;               // Lsel >= 1 always
    out[(size_t)bsel * 32 + lm] = pooled;                  // both halves write

    float contrib = pooled * w_cls[lm];
#pragma unroll
    for (int off = 16; off > 0; off >>= 1)                 // reduce within half
        contrib += __shfl_down(contrib, off, 32);
    if (lm == 0)
        out[(size_t)B * 32 + bsel] = fast_sigmoid(contrib + b_cls[0]);
}

extern "C" void kernel_launch(void* const* d_in, const int* in_sizes, int n_in,
                              void* d_out, int out_size, void* d_ws, size_t ws_size,
                              hipStream_t stream)
{
    const float* x     = (const float*)d_in[0];
    const float* mask  = (const float*)d_in[1];
    const float* w_ih  = (const float*)d_in[2];
    const float* w_hh  = (const float*)d_in[3];
    const float* b_ih  = (const float*)d_in[4];
    const float* b_hh  = (const float*)d_in[5];
    const float* w_cls = (const float*)d_in[6];
    const float* b_cls = (const float*)d_in[7];
    float* out = (float*)d_out;

    const int B = out_size / 33;        // pooled B*32 + probs B
    const int T = in_sizes[1] / B;      // mask is [B,T]

    int* lens = (int*)d_ws;
    int* sidx = lens + B;

    len_kernel<<<B, 64, 0, stream>>>(mask, lens, B, T);
    sort_kernel<<<1, 1024, 0, stream>>>(lens, sidx, B, T);
    lstm_main<<<B / 2, 64, 0, stream>>>(x, lens, sidx, w_ih, w_hh, b_ih, b_hh,
                                        w_cls, b_cls, out, B, T);
}